// Round 1
// baseline (2228.358 us; speedup 1.0000x reference)
//
#include <hip/hip_runtime.h>
#include <hip/hip_bf16.h>

#define H2 2048     // student hidden
#define HT 4096     // teacher hidden
#define NV 32000    // vocab
#define NBT 2048    // batch*time rows
#define BM 128
#define BN 128
#define BK 32
#define LDT 40      // LDS row stride (elems): 32 + 8 pad -> <=2-way bank alias
#define NVB (NV / BN)   // 250

typedef __attribute__((ext_vector_type(8))) short short8;
typedef __attribute__((ext_vector_type(8))) unsigned short ushort8;
typedef __attribute__((ext_vector_type(4))) float floatx4;

static __device__ __forceinline__ unsigned int pk_bf16(float a, float b) {
  __hip_bfloat162 h = __float22bfloat162_rn(make_float2(a, b));
  union { __hip_bfloat162 h; unsigned int u; } c;
  c.h = h;
  return c.u;
}

// fp32 -> bf16 (bits) conversion, 8 elems/thread
__global__ void cvt_bf16_kernel(const float* __restrict__ src,
                                unsigned int* __restrict__ dst, int n) {
  int i = blockIdx.x * blockDim.x + threadIdx.x;
  int base = i * 8;
  if (base >= n) return;
  float4 f0 = *(const float4*)(src + base);
  float4 f1 = *(const float4*)(src + base + 4);
  uint4 o;
  o.x = pk_bf16(f0.x, f0.y);
  o.y = pk_bf16(f0.z, f0.w);
  o.z = pk_bf16(f1.x, f1.y);
  o.w = pk_bf16(f1.z, f1.w);
  *(uint4*)(dst + i * 4) = o;
}

// Fused dual-GEMM + per-row partial reductions over a 128x128 tile.
__global__ __launch_bounds__(256, 2) void fused_gemm_kernel(
    const unsigned short* __restrict__ sbf,   // [NBT][H2] bf16 bits
    const unsigned short* __restrict__ tbf,   // [NBT][HT] bf16 bits
    const float* __restrict__ Ws,             // [NV][H2] fp32
    const float* __restrict__ Wt,             // [NV][HT] fp32
    const int* __restrict__ target,           // [NBT]
    float* __restrict__ part,                 // [NVB][4][NBT]
    float* __restrict__ s_tgt_out)            // [NBT]
{
  __shared__ unsigned short sA[BM * LDT];
  __shared__ unsigned short sB[BN * LDT];
  __shared__ float sRed[BM][4];
  __shared__ int sTgt[BM];

  const int tid = threadIdx.x;
  const int row0 = blockIdx.x * BM;   // 16 row-blocks (fast dim -> L2 reuse of W)
  const int col0 = blockIdx.y * BN;   // 250 vocab-blocks (slow dim)
  const int lane = tid & 63;
  const int wv = tid >> 6;
  const int wr = wv >> 1;
  const int wc = wv & 1;

  if (tid < BM) {
    sTgt[tid] = target[row0 + tid];
    sRed[tid][0] = 0.f; sRed[tid][1] = 0.f;
    sRed[tid][2] = 0.f; sRed[tid][3] = 0.f;
  }

  floatx4 acc_s[4][4];
  floatx4 acc_t[4][4];
#pragma unroll
  for (int i = 0; i < 4; ++i)
#pragma unroll
    for (int j = 0; j < 4; ++j) {
      acc_s[i][j] = (floatx4){0.f, 0.f, 0.f, 0.f};
      acc_t[i][j] = (floatx4){0.f, 0.f, 0.f, 0.f};
    }

  // staging assignment: thread -> (row sr, k-halve sk)
  const int sr = tid >> 1;            // 0..127
  const int sk = (tid & 1) << 4;      // 0 or 16

  // fragment addresses (16x16x32: A row = lane&15, k = (lane>>4)*8 + 0..7)
  const int mrow = lane & 15;
  const int koff = (lane >> 4) << 3;
  const int abase = (wr * 64 + mrow) * LDT + koff;
  const int bbase = (wc * 64 + mrow) * LDT + koff;

  // ---------------- student phase (K = H2) ----------------
  {
    const unsigned short* ap = sbf + (size_t)(row0 + sr) * H2 + sk;
    const float* bp = Ws + (size_t)(col0 + sr) * H2 + sk;
#pragma unroll 1
    for (int k0 = 0; k0 < H2; k0 += BK) {
      ushort8 a0 = *(const ushort8*)(ap);
      ushort8 a1 = *(const ushort8*)(ap + 8);
      float4 b0 = *(const float4*)(bp);
      float4 b1 = *(const float4*)(bp + 4);
      float4 b2 = *(const float4*)(bp + 8);
      float4 b3 = *(const float4*)(bp + 12);
      ap += BK; bp += BK;
      __syncthreads();
      *(ushort8*)(&sA[sr * LDT + sk]) = a0;
      *(ushort8*)(&sA[sr * LDT + sk + 8]) = a1;
      uint4 u0, u1;
      u0.x = pk_bf16(b0.x, b0.y); u0.y = pk_bf16(b0.z, b0.w);
      u0.z = pk_bf16(b1.x, b1.y); u0.w = pk_bf16(b1.z, b1.w);
      u1.x = pk_bf16(b2.x, b2.y); u1.y = pk_bf16(b2.z, b2.w);
      u1.z = pk_bf16(b3.x, b3.y); u1.w = pk_bf16(b3.z, b3.w);
      *(uint4*)(&sB[sr * LDT + sk]) = u0;
      *(uint4*)(&sB[sr * LDT + sk + 8]) = u1;
      __syncthreads();
      short8 af[4], bfrag[4];
#pragma unroll
      for (int i = 0; i < 4; ++i)
        af[i] = *(const short8*)(&sA[abase + i * 16 * LDT]);
#pragma unroll
      for (int j = 0; j < 4; ++j)
        bfrag[j] = *(const short8*)(&sB[bbase + j * 16 * LDT]);
#pragma unroll
      for (int i = 0; i < 4; ++i)
#pragma unroll
        for (int j = 0; j < 4; ++j)
          acc_s[i][j] = __builtin_amdgcn_mfma_f32_16x16x32_bf16(
              af[i], bfrag[j], acc_s[i][j], 0, 0, 0);
    }
  }

  // ---------------- teacher phase (K = HT) ----------------
  {
    const unsigned short* ap = tbf + (size_t)(row0 + sr) * HT + sk;
    const float* bp = Wt + (size_t)(col0 + sr) * HT + sk;
#pragma unroll 1
    for (int k0 = 0; k0 < HT; k0 += BK) {
      ushort8 a0 = *(const ushort8*)(ap);
      ushort8 a1 = *(const ushort8*)(ap + 8);
      float4 b0 = *(const float4*)(bp);
      float4 b1 = *(const float4*)(bp + 4);
      float4 b2 = *(const float4*)(bp + 8);
      float4 b3 = *(const float4*)(bp + 12);
      ap += BK; bp += BK;
      __syncthreads();
      *(ushort8*)(&sA[sr * LDT + sk]) = a0;
      *(ushort8*)(&sA[sr * LDT + sk + 8]) = a1;
      uint4 u0, u1;
      u0.x = pk_bf16(b0.x, b0.y); u0.y = pk_bf16(b0.z, b0.w);
      u0.z = pk_bf16(b1.x, b1.y); u0.w = pk_bf16(b1.z, b1.w);
      u1.x = pk_bf16(b2.x, b2.y); u1.y = pk_bf16(b2.z, b2.w);
      u1.z = pk_bf16(b3.x, b3.y); u1.w = pk_bf16(b3.z, b3.w);
      *(uint4*)(&sB[sr * LDT + sk]) = u0;
      *(uint4*)(&sB[sr * LDT + sk + 8]) = u1;
      __syncthreads();
      short8 af[4], bfrag[4];
#pragma unroll
      for (int i = 0; i < 4; ++i)
        af[i] = *(const short8*)(&sA[abase + i * 16 * LDT]);
#pragma unroll
      for (int j = 0; j < 4; ++j)
        bfrag[j] = *(const short8*)(&sB[bbase + j * 16 * LDT]);
#pragma unroll
      for (int i = 0; i < 4; ++i)
#pragma unroll
        for (int j = 0; j < 4; ++j)
          acc_t[i][j] = __builtin_amdgcn_mfma_f32_16x16x32_bf16(
              af[i], bfrag[j], acc_t[i][j], 0, 0, 0);
    }
  }

  // ---------------- epilogue: per-row partials ----------------
  // C layout (16x16x32): col = lane&15, row = (lane>>4)*4 + reg   [m89]
#pragma unroll
  for (int i = 0; i < 4; ++i) {
#pragma unroll
    for (int r = 0; r < 4; ++r) {
      const int row_l = wr * 64 + i * 16 + (lane >> 4) * 4 + r;
      float e = 0.f, dp = 0.f, ss = 0.f, tt = 0.f;
#pragma unroll
      for (int j = 0; j < 4; ++j) {
        float s = acc_s[i][j][r];
        float t = acc_t[i][j][r];
        e += __expf(s);
        dp += s * t;
        ss += s * s;
        tt += t * t;
        const int col_l = wc * 64 + j * 16 + (lane & 15);
        if (sTgt[row_l] == col0 + col_l) s_tgt_out[row0 + row_l] = s;
      }
#pragma unroll
      for (int off = 1; off < 16; off <<= 1) {
        e  += __shfl_xor(e,  off, 16);
        dp += __shfl_xor(dp, off, 16);
        ss += __shfl_xor(ss, off, 16);
        tt += __shfl_xor(tt, off, 16);
      }
      if ((lane & 15) == 0) {
        atomicAdd(&sRed[row_l][0], e);
        atomicAdd(&sRed[row_l][1], dp);
        atomicAdd(&sRed[row_l][2], ss);
        atomicAdd(&sRed[row_l][3], tt);
      }
    }
  }
  __syncthreads();
  if (tid < BM) {
    float* p = part + (size_t)blockIdx.y * 4 * NBT + row0 + tid;
    p[0]       = sRed[tid][0];
    p[NBT]     = sRed[tid][1];
    p[2 * NBT] = sRed[tid][2];
    p[3 * NBT] = sRed[tid][3];
  }
}

__global__ void row_loss_kernel(const float* __restrict__ part,
                                const float* __restrict__ s_tgt,
                                const int* __restrict__ target,
                                float* __restrict__ row_loss) {
  const int row = blockIdx.x * blockDim.x + threadIdx.x;
  if (row >= NBT) return;
  float e = 0.f, dp = 0.f, ss = 0.f, tt = 0.f;
  for (int v = 0; v < NVB; ++v) {
    const float* p = part + (size_t)v * 4 * NBT + row;
    e  += p[0];
    dp += p[NBT];
    ss += p[2 * NBT];
    tt += p[3 * NBT];
  }
  const float lse = logf(e);
  const int tg = target[row];
  const float st = s_tgt[row];
  const float nll = (tg != -100) ? (lse - st) : 0.f;
  const float ns = fmaxf(sqrtf(ss), 1e-12f);
  const float nt = fmaxf(sqrtf(tt), 1e-12f);
  const float c = dp / (ns * nt);
  row_loss[row] = (0.5f * nll + 0.5f * (1.f - c)) * (1.f / (float)NBT);
}

__global__ void final_reduce_kernel(const float* __restrict__ row_loss,
                                    float* __restrict__ out) {
  __shared__ float sm[4];
  float v = 0.f;
  for (int i = threadIdx.x; i < NBT; i += 256) v += row_loss[i];
#pragma unroll
  for (int off = 32; off >= 1; off >>= 1) v += __shfl_down(v, off, 64);
  if ((threadIdx.x & 63) == 0) sm[threadIdx.x >> 6] = v;
  __syncthreads();
  if (threadIdx.x == 0) out[0] = sm[0] + sm[1] + sm[2] + sm[3];
}

extern "C" void kernel_launch(void* const* d_in, const int* in_sizes, int n_in,
                              void* d_out, int out_size, void* d_ws, size_t ws_size,
                              hipStream_t stream) {
  const float* student = (const float*)d_in[0];  // [2048][2048]
  const float* Ws      = (const float*)d_in[1];  // [32000][2048]
  const float* teacher = (const float*)d_in[2];  // [2048][4096]
  const float* Wt      = (const float*)d_in[3];  // [32000][4096]
  const int*   target  = (const int*)d_in[4];    // [2048]

  // workspace layout (~33 MB)
  unsigned short* sbf = (unsigned short*)d_ws;            // NBT*H2 bf16
  unsigned short* tbf = sbf + (size_t)NBT * H2;           // NBT*HT bf16
  float* part     = (float*)(tbf + (size_t)NBT * HT);     // NVB*4*NBT f32
  float* s_tgt    = part + (size_t)NVB * 4 * NBT;         // NBT f32
  float* row_loss = s_tgt + NBT;                          // NBT f32

  {
    int n = NBT * H2;
    cvt_bf16_kernel<<<(n / 8 + 255) / 256, 256, 0, stream>>>(
        student, (unsigned int*)sbf, n);
  }
  {
    int n = NBT * HT;
    cvt_bf16_kernel<<<(n / 8 + 255) / 256, 256, 0, stream>>>(
        teacher, (unsigned int*)tbf, n);
  }

  dim3 grid(NBT / BM, NV / BN);   // (16, 250): row-blocks fast for W reuse in L2
  fused_gemm_kernel<<<grid, 256, 0, stream>>>(sbf, tbf, Ws, Wt, target,
                                              part, s_tgt);

  row_loss_kernel<<<NBT / 256, 256, 0, stream>>>(part, s_tgt, target, row_loss);
  final_reduce_kernel<<<1, 256, 0, stream>>>(row_loss, (float*)d_out);
}

// Round 2
// 1998.514 us; speedup vs baseline: 1.1150x; 1.1150x over previous
//
#include <hip/hip_runtime.h>
#include <hip/hip_bf16.h>

#define H2 2048     // student hidden
#define HT 4096     // teacher hidden
#define NV 32000    // vocab
#define NBT 2048    // batch*time rows
#define BM 128
#define BN 128
#define BK 32
#define LDT 40      // fallback-path LDS stride
#define NVB (NV / BN)   // 250

typedef __attribute__((ext_vector_type(8))) short short8;
typedef __attribute__((ext_vector_type(8))) unsigned short ushort8;
typedef __attribute__((ext_vector_type(4))) float floatx4;

static __device__ __forceinline__ unsigned int pk_bf16(float a, float b) {
  __hip_bfloat162 h = __float22bfloat162_rn(make_float2(a, b));
  union { __hip_bfloat162 h; unsigned int u; } c;
  c.h = h;
  return c.u;
}

// direct global->LDS DMA, 16 B per lane (m97: the 517->874 TF step)
static __device__ __forceinline__ void gload_lds16(const void* g, void* l) {
  __builtin_amdgcn_global_load_lds(
      (const __attribute__((address_space(1))) unsigned int*)g,
      (__attribute__((address_space(3))) unsigned int*)l, 16, 0, 0);
}

// fp32 -> bf16 (bits) conversion, 8 elems/thread
__global__ void cvt_bf16_kernel(const float* __restrict__ src,
                                unsigned int* __restrict__ dst, int n) {
  int i = blockIdx.x * blockDim.x + threadIdx.x;
  int base = i * 8;
  if (base >= n) return;
  float4 f0 = *(const float4*)(src + base);
  float4 f1 = *(const float4*)(src + base + 4);
  uint4 o;
  o.x = pk_bf16(f0.x, f0.y);
  o.y = pk_bf16(f0.z, f0.w);
  o.z = pk_bf16(f1.x, f1.y);
  o.w = pk_bf16(f1.z, f1.w);
  *(uint4*)(dst + i * 4) = o;
}

// ---------------------------------------------------------------------------
// Primary path: all-bf16 GEMM with global_load_lds staging (m97 structure)
// ---------------------------------------------------------------------------

template <int K>
static __device__ __forceinline__ void gemm_phase(
    const unsigned short* __restrict__ act,   // [.][K] bf16 bits
    const unsigned short* __restrict__ w,     // [.][K] bf16 bits
    int row0, int col0, int tid,
    unsigned short* sA, unsigned short* sB,
    int abase, int bbase, floatx4 (&acc)[4][4])
{
  // staging: flat = issue*256 + tid covers 16 B; row = flat>>2, col8 = flat&3
  const int r0 = tid >> 2;
  const int c0 = (tid & 3) * 8;
  const unsigned short* a0 = act + (size_t)(row0 + r0) * K + c0;
  const unsigned short* a1 = act + (size_t)(row0 + r0 + 64) * K + c0;
  const unsigned short* b0 = w + (size_t)(col0 + r0) * K + c0;
  const unsigned short* b1 = w + (size_t)(col0 + r0 + 64) * K + c0;
  unsigned short* lA0 = sA + tid * 8;          // lane-contiguous (DMA rule)
  unsigned short* lA1 = sA + (256 + tid) * 8;
  unsigned short* lB0 = sB + tid * 8;
  unsigned short* lB1 = sB + (256 + tid) * 8;

#pragma unroll 1
  for (int k0 = 0; k0 < K; k0 += BK) {
    __syncthreads();   // previous iter's ds_reads done before overwrite
    gload_lds16(a0, lA0);
    gload_lds16(a1, lA1);
    gload_lds16(b0, lB0);
    gload_lds16(b1, lB1);
    a0 += BK; a1 += BK; b0 += BK; b1 += BK;
    __syncthreads();   // vmcnt drain -> tiles visible
    short8 af[4], bf[4];
#pragma unroll
    for (int i = 0; i < 4; ++i)
      af[i] = *(const short8*)(sA + abase + i * 16 * BK);
#pragma unroll
    for (int j = 0; j < 4; ++j)
      bf[j] = *(const short8*)(sB + bbase + j * 16 * BK);
#pragma unroll
    for (int i = 0; i < 4; ++i)
#pragma unroll
      for (int j = 0; j < 4; ++j)
        acc[i][j] = __builtin_amdgcn_mfma_f32_16x16x32_bf16(
            af[i], bf[j], acc[i][j], 0, 0, 0);
  }
}

__global__ __launch_bounds__(256, 2) void fused_gemm_lds_kernel(
    const unsigned short* __restrict__ sbf,   // [NBT][H2] bf16
    const unsigned short* __restrict__ tbf,   // [NBT][HT] bf16
    const unsigned short* __restrict__ Wsb,   // [NV][H2] bf16
    const unsigned short* __restrict__ Wtb,   // [NV][HT] bf16
    const int* __restrict__ target,
    float* __restrict__ part,                 // [NVB][4][NBT]
    float* __restrict__ s_tgt_out)            // [NBT]
{
  __shared__ unsigned short sA[BM * BK];   // 8 KB, unpadded (DMA layout)
  __shared__ unsigned short sB[BN * BK];   // 8 KB
  __shared__ float sRed[BM][4];
  __shared__ int sTgt[BM];

  const int tid = threadIdx.x;
  const int row0 = blockIdx.x * BM;
  const int col0 = blockIdx.y * BN;
  const int lane = tid & 63;
  const int wv = tid >> 6;
  const int wr = wv >> 1;
  const int wc = wv & 1;

  if (tid < BM) {
    sTgt[tid] = target[row0 + tid];
    sRed[tid][0] = 0.f; sRed[tid][1] = 0.f;
    sRed[tid][2] = 0.f; sRed[tid][3] = 0.f;
  }

  floatx4 acc_s[4][4];
  floatx4 acc_t[4][4];
#pragma unroll
  for (int i = 0; i < 4; ++i)
#pragma unroll
    for (int j = 0; j < 4; ++j) {
      acc_s[i][j] = (floatx4){0.f, 0.f, 0.f, 0.f};
      acc_t[i][j] = (floatx4){0.f, 0.f, 0.f, 0.f};
    }

  // fragment read addresses (short-index): row-major [128][32]
  const int mrow = lane & 15;
  const int koff = (lane >> 4) * 8;
  const int abase = (wr * 64 + mrow) * BK + koff;
  const int bbase = (wc * 64 + mrow) * BK + koff;

  gemm_phase<H2>(sbf, Wsb, row0, col0, tid, sA, sB, abase, bbase, acc_s);
  gemm_phase<HT>(tbf, Wtb, row0, col0, tid, sA, sB, abase, bbase, acc_t);

  // epilogue: per-row partials. C layout: col=lane&15, row=(lane>>4)*4+reg
#pragma unroll
  for (int i = 0; i < 4; ++i) {
#pragma unroll
    for (int r = 0; r < 4; ++r) {
      const int row_l = wr * 64 + i * 16 + (lane >> 4) * 4 + r;
      float e = 0.f, dp = 0.f, ss = 0.f, tt = 0.f;
#pragma unroll
      for (int j = 0; j < 4; ++j) {
        float s = acc_s[i][j][r];
        float t = acc_t[i][j][r];
        e += __expf(s);
        dp += s * t;
        ss += s * s;
        tt += t * t;
        const int col_l = wc * 64 + j * 16 + (lane & 15);
        if (sTgt[row_l] == col0 + col_l) s_tgt_out[row0 + row_l] = s;
      }
#pragma unroll
      for (int off = 1; off < 16; off <<= 1) {
        e  += __shfl_xor(e,  off, 16);
        dp += __shfl_xor(dp, off, 16);
        ss += __shfl_xor(ss, off, 16);
        tt += __shfl_xor(tt, off, 16);
      }
      if ((lane & 15) == 0) {
        atomicAdd(&sRed[row_l][0], e);
        atomicAdd(&sRed[row_l][1], dp);
        atomicAdd(&sRed[row_l][2], ss);
        atomicAdd(&sRed[row_l][3], tt);
      }
    }
  }
  __syncthreads();
  if (tid < BM) {
    float* p = part + (size_t)blockIdx.y * 4 * NBT + row0 + tid;
    p[0]       = sRed[tid][0];
    p[NBT]     = sRed[tid][1];
    p[2 * NBT] = sRed[tid][2];
    p[3 * NBT] = sRed[tid][3];
  }
}

// ---------------------------------------------------------------------------
// Fallback path (round-1 kernel): fp32 weights, in-loop cvt — used only if
// ws_size can't hold the bf16 weight copies.
// ---------------------------------------------------------------------------

__global__ __launch_bounds__(256, 2) void fused_gemm_kernel(
    const unsigned short* __restrict__ sbf,
    const unsigned short* __restrict__ tbf,
    const float* __restrict__ Ws,
    const float* __restrict__ Wt,
    const int* __restrict__ target,
    float* __restrict__ part,
    float* __restrict__ s_tgt_out)
{
  __shared__ unsigned short sA[BM * LDT];
  __shared__ unsigned short sB[BN * LDT];
  __shared__ float sRed[BM][4];
  __shared__ int sTgt[BM];

  const int tid = threadIdx.x;
  const int row0 = blockIdx.x * BM;
  const int col0 = blockIdx.y * BN;
  const int lane = tid & 63;
  const int wv = tid >> 6;
  const int wr = wv >> 1;
  const int wc = wv & 1;

  if (tid < BM) {
    sTgt[tid] = target[row0 + tid];
    sRed[tid][0] = 0.f; sRed[tid][1] = 0.f;
    sRed[tid][2] = 0.f; sRed[tid][3] = 0.f;
  }

  floatx4 acc_s[4][4];
  floatx4 acc_t[4][4];
#pragma unroll
  for (int i = 0; i < 4; ++i)
#pragma unroll
    for (int j = 0; j < 4; ++j) {
      acc_s[i][j] = (floatx4){0.f, 0.f, 0.f, 0.f};
      acc_t[i][j] = (floatx4){0.f, 0.f, 0.f, 0.f};
    }

  const int sr = tid >> 1;
  const int sk = (tid & 1) << 4;
  const int mrow = lane & 15;
  const int koff = (lane >> 4) << 3;
  const int abase = (wr * 64 + mrow) * LDT + koff;
  const int bbase = (wc * 64 + mrow) * LDT + koff;

  {
    const unsigned short* ap = sbf + (size_t)(row0 + sr) * H2 + sk;
    const float* bp = Ws + (size_t)(col0 + sr) * H2 + sk;
#pragma unroll 1
    for (int k0 = 0; k0 < H2; k0 += BK) {
      ushort8 a0 = *(const ushort8*)(ap);
      ushort8 a1 = *(const ushort8*)(ap + 8);
      float4 b0 = *(const float4*)(bp);
      float4 b1 = *(const float4*)(bp + 4);
      float4 b2 = *(const float4*)(bp + 8);
      float4 b3 = *(const float4*)(bp + 12);
      ap += BK; bp += BK;
      __syncthreads();
      *(ushort8*)(&sA[sr * LDT + sk]) = a0;
      *(ushort8*)(&sA[sr * LDT + sk + 8]) = a1;
      uint4 u0, u1;
      u0.x = pk_bf16(b0.x, b0.y); u0.y = pk_bf16(b0.z, b0.w);
      u0.z = pk_bf16(b1.x, b1.y); u0.w = pk_bf16(b1.z, b1.w);
      u1.x = pk_bf16(b2.x, b2.y); u1.y = pk_bf16(b2.z, b2.w);
      u1.z = pk_bf16(b3.x, b3.y); u1.w = pk_bf16(b3.z, b3.w);
      *(uint4*)(&sB[sr * LDT + sk]) = u0;
      *(uint4*)(&sB[sr * LDT + sk + 8]) = u1;
      __syncthreads();
      short8 af[4], bfrag[4];
#pragma unroll
      for (int i = 0; i < 4; ++i)
        af[i] = *(const short8*)(&sA[abase + i * 16 * LDT]);
#pragma unroll
      for (int j = 0; j < 4; ++j)
        bfrag[j] = *(const short8*)(&sB[bbase + j * 16 * LDT]);
#pragma unroll
      for (int i = 0; i < 4; ++i)
#pragma unroll
        for (int j = 0; j < 4; ++j)
          acc_s[i][j] = __builtin_amdgcn_mfma_f32_16x16x32_bf16(
              af[i], bfrag[j], acc_s[i][j], 0, 0, 0);
    }
  }
  {
    const unsigned short* ap = tbf + (size_t)(row0 + sr) * HT + sk;
    const float* bp = Wt + (size_t)(col0 + sr) * HT + sk;
#pragma unroll 1
    for (int k0 = 0; k0 < HT; k0 += BK) {
      ushort8 a0 = *(const ushort8*)(ap);
      ushort8 a1 = *(const ushort8*)(ap + 8);
      float4 b0 = *(const float4*)(bp);
      float4 b1 = *(const float4*)(bp + 4);
      float4 b2 = *(const float4*)(bp + 8);
      float4 b3 = *(const float4*)(bp + 12);
      ap += BK; bp += BK;
      __syncthreads();
      *(ushort8*)(&sA[sr * LDT + sk]) = a0;
      *(ushort8*)(&sA[sr * LDT + sk + 8]) = a1;
      uint4 u0, u1;
      u0.x = pk_bf16(b0.x, b0.y); u0.y = pk_bf16(b0.z, b0.w);
      u0.z = pk_bf16(b1.x, b1.y); u0.w = pk_bf16(b1.z, b1.w);
      u1.x = pk_bf16(b2.x, b2.y); u1.y = pk_bf16(b2.z, b2.w);
      u1.z = pk_bf16(b3.x, b3.y); u1.w = pk_bf16(b3.z, b3.w);
      *(uint4*)(&sB[sr * LDT + sk]) = u0;
      *(uint4*)(&sB[sr * LDT + sk + 8]) = u1;
      __syncthreads();
      short8 af[4], bfrag[4];
#pragma unroll
      for (int i = 0; i < 4; ++i)
        af[i] = *(const short8*)(&sA[abase + i * 16 * LDT]);
#pragma unroll
      for (int j = 0; j < 4; ++j)
        bfrag[j] = *(const short8*)(&sB[bbase + j * 16 * LDT]);
#pragma unroll
      for (int i = 0; i < 4; ++i)
#pragma unroll
        for (int j = 0; j < 4; ++j)
          acc_t[i][j] = __builtin_amdgcn_mfma_f32_16x16x32_bf16(
              af[i], bfrag[j], acc_t[i][j], 0, 0, 0);
    }
  }

#pragma unroll
  for (int i = 0; i < 4; ++i) {
#pragma unroll
    for (int r = 0; r < 4; ++r) {
      const int row_l = wr * 64 + i * 16 + (lane >> 4) * 4 + r;
      float e = 0.f, dp = 0.f, ss = 0.f, tt = 0.f;
#pragma unroll
      for (int j = 0; j < 4; ++j) {
        float s = acc_s[i][j][r];
        float t = acc_t[i][j][r];
        e += __expf(s);
        dp += s * t;
        ss += s * s;
        tt += t * t;
        const int col_l = wc * 64 + j * 16 + (lane & 15);
        if (sTgt[row_l] == col0 + col_l) s_tgt_out[row0 + row_l] = s;
      }
#pragma unroll
      for (int off = 1; off < 16; off <<= 1) {
        e  += __shfl_xor(e,  off, 16);
        dp += __shfl_xor(dp, off, 16);
        ss += __shfl_xor(ss, off, 16);
        tt += __shfl_xor(tt, off, 16);
      }
      if ((lane & 15) == 0) {
        atomicAdd(&sRed[row_l][0], e);
        atomicAdd(&sRed[row_l][1], dp);
        atomicAdd(&sRed[row_l][2], ss);
        atomicAdd(&sRed[row_l][3], tt);
      }
    }
  }
  __syncthreads();
  if (tid < BM) {
    float* p = part + (size_t)blockIdx.y * 4 * NBT + row0 + tid;
    p[0]       = sRed[tid][0];
    p[NBT]     = sRed[tid][1];
    p[2 * NBT] = sRed[tid][2];
    p[3 * NBT] = sRed[tid][3];
  }
}

// ---------------------------------------------------------------------------

__global__ void row_loss_kernel(const float* __restrict__ part,
                                const float* __restrict__ s_tgt,
                                const int* __restrict__ target,
                                float* __restrict__ row_loss) {
  const int row = blockIdx.x * blockDim.x + threadIdx.x;
  if (row >= NBT) return;
  float e = 0.f, dp = 0.f, ss = 0.f, tt = 0.f;
  for (int v = 0; v < NVB; ++v) {
    const float* p = part + (size_t)v * 4 * NBT + row;
    e  += p[0];
    dp += p[NBT];
    ss += p[2 * NBT];
    tt += p[3 * NBT];
  }
  const float lse = logf(e);
  const int tg = target[row];
  const float st = s_tgt[row];
  const float nll = (tg != -100) ? (lse - st) : 0.f;
  const float ns = fmaxf(sqrtf(ss), 1e-12f);
  const float nt = fmaxf(sqrtf(tt), 1e-12f);
  const float c = dp / (ns * nt);
  row_loss[row] = (0.5f * nll + 0.5f * (1.f - c)) * (1.f / (float)NBT);
}

__global__ void final_reduce_kernel(const float* __restrict__ row_loss,
                                    float* __restrict__ out) {
  __shared__ float sm[4];
  float v = 0.f;
  for (int i = threadIdx.x; i < NBT; i += 256) v += row_loss[i];
#pragma unroll
  for (int off = 32; off >= 1; off >>= 1) v += __shfl_down(v, off, 64);
  if ((threadIdx.x & 63) == 0) sm[threadIdx.x >> 6] = v;
  __syncthreads();
  if (threadIdx.x == 0) out[0] = sm[0] + sm[1] + sm[2] + sm[3];
}

extern "C" void kernel_launch(void* const* d_in, const int* in_sizes, int n_in,
                              void* d_out, int out_size, void* d_ws, size_t ws_size,
                              hipStream_t stream) {
  const float* student = (const float*)d_in[0];  // [2048][2048]
  const float* Ws      = (const float*)d_in[1];  // [32000][2048]
  const float* teacher = (const float*)d_in[2];  // [2048][4096]
  const float* Wt      = (const float*)d_in[3];  // [32000][4096]
  const int*   target  = (const int*)d_in[4];    // [2048]

  const size_t nS  = (size_t)NBT * H2;   //  4.19 M
  const size_t nT  = (size_t)NBT * HT;   //  8.39 M
  const size_t nWs = (size_t)NV * H2;    // 65.5 M
  const size_t nWt = (size_t)NV * HT;    // 131 M
  const size_t nPart = (size_t)NVB * 4 * NBT;

  const size_t ws_needed_big =
      (nS + nT + nWs + nWt) * 2 + (nPart + 2 * NBT) * 4;

  if (ws_size >= ws_needed_big) {
    // primary path: bf16 everything + global_load_lds staging
    unsigned short* sbf = (unsigned short*)d_ws;
    unsigned short* tbf = sbf + nS;
    unsigned short* Wsb = tbf + nT;
    unsigned short* Wtb = Wsb + nWs;
    float* part     = (float*)(Wtb + nWt);
    float* s_tgt    = part + nPart;
    float* row_loss = s_tgt + NBT;

    cvt_bf16_kernel<<<(int)(nS / 8 / 256), 256, 0, stream>>>(
        student, (unsigned int*)sbf, (int)nS);
    cvt_bf16_kernel<<<(int)(nT / 8 / 256), 256, 0, stream>>>(
        teacher, (unsigned int*)tbf, (int)nT);
    cvt_bf16_kernel<<<(int)(nWs / 8 / 256), 256, 0, stream>>>(
        Ws, (unsigned int*)Wsb, (int)nWs);
    cvt_bf16_kernel<<<(int)(nWt / 8 / 256), 256, 0, stream>>>(
        Wt, (unsigned int*)Wtb, (int)nWt);

    dim3 grid(NBT / BM, NV / BN);   // (16, 250)
    fused_gemm_lds_kernel<<<grid, 256, 0, stream>>>(
        sbf, tbf, Wsb, Wtb, target, part, s_tgt);

    row_loss_kernel<<<NBT / 256, 256, 0, stream>>>(part, s_tgt, target, row_loss);
    final_reduce_kernel<<<1, 256, 0, stream>>>(row_loss, (float*)d_out);
  } else {
    // fallback: round-1 path (fp32 weights, in-loop cvt)
    unsigned short* sbf = (unsigned short*)d_ws;
    unsigned short* tbf = sbf + nS;
    float* part     = (float*)(tbf + nT);
    float* s_tgt    = part + nPart;
    float* row_loss = s_tgt + NBT;

    cvt_bf16_kernel<<<(int)(nS / 8 / 256), 256, 0, stream>>>(
        student, (unsigned int*)sbf, (int)nS);
    cvt_bf16_kernel<<<(int)(nT / 8 / 256), 256, 0, stream>>>(
        teacher, (unsigned int*)tbf, (int)nT);

    dim3 grid(NBT / BM, NV / BN);
    fused_gemm_kernel<<<grid, 256, 0, stream>>>(sbf, tbf, Ws, Wt, target,
                                                part, s_tgt);

    row_loss_kernel<<<NBT / 256, 256, 0, stream>>>(part, s_tgt, target, row_loss);
    final_reduce_kernel<<<1, 256, 0, stream>>>(row_loss, (float*)d_out);
  }
}